// Round 1
// baseline (3571.631 us; speedup 1.0000x reference)
//
#include <hip/hip_runtime.h>
#include <hip/hip_bf16.h>

// RelativeSemanticLoss: nll = mean over valid pixels of
//   lse_k(dot(pred[b,:,h,w], cls[k,:])/T) - dot(pred[b,:,h,w], cls[label,:])/T
// B=4, D=512, H=W=256, K=150 classes, T=0.07, IGNORE=255.

#define NUM_CLS 150
#define D_DIM   512
#define B_DIM   4
#define HW_DIM  65536   // 256*256
#define IGNORE_L 255

// d_ws layout: [0..7] double sum, [8..15] u64 count
__global__ __launch_bounds__(256, 2)
void rsl_main(const float* __restrict__ pred,
              const float* __restrict__ cls,
              const int*   __restrict__ idx,
              const int*   __restrict__ lut,
              double* __restrict__ ws_sum,
              unsigned long long* __restrict__ ws_cnt)
{
    const int pid = blockIdx.x * blockDim.x + threadIdx.x;   // 0 .. B*HW-1
    const int b = pid >> 16;          // / HW_DIM
    const int p = pid & 0xFFFF;       // % HW_DIM
    const float* pb = pred + ((size_t)b * D_DIM) * HW_DIM + p;

    float acc[NUM_CLS];
#pragma unroll
    for (int k = 0; k < NUM_CLS; ++k) acc[k] = 0.f;

    // d-chunked: 8 coalesced strided loads, then 150x8 FMAs with
    // wave-uniform cls reads (compiler -> s_load + SGPR operand of v_fma)
    for (int d0 = 0; d0 < D_DIM; d0 += 8) {
        float pr[8];
#pragma unroll
        for (int j = 0; j < 8; ++j)
            pr[j] = pb[(size_t)(d0 + j) * HW_DIM];
#pragma unroll
        for (int k = 0; k < NUM_CLS; ++k) {
#pragma unroll
            for (int j = 0; j < 8; ++j)
                acc[k] = fmaf(cls[k * D_DIM + d0 + j], pr[j], acc[k]);
        }
    }

    const int label = lut[idx[pid]];
    const bool valid = (label != IGNORE_L);

    const float invT = 1.0f / 0.07f;
    float m = -INFINITY;
#pragma unroll
    for (int k = 0; k < NUM_CLS; ++k) m = fmaxf(m, acc[k]);

    float s = 0.f;
    float lbl = 0.f;   // static-index pick of acc[label] (rule #20: no runtime indexing)
#pragma unroll
    for (int k = 0; k < NUM_CLS; ++k) {
        s += __expf((acc[k] - m) * invT);
        lbl = (k == label) ? acc[k] : lbl;
    }
    // nll = lse - sim[label]; sim = acc*invT
    float nll = (m - lbl) * invT + __logf(s);

    float v = valid ? nll : 0.f;
    int   c = valid ? 1 : 0;

    // wave(64) reduction
#pragma unroll
    for (int off = 32; off > 0; off >>= 1) {
        v += __shfl_down(v, off);
        c += __shfl_down(c, off);
    }

    __shared__ float sv[4];
    __shared__ int   sc[4];
    const int wid  = threadIdx.x >> 6;
    const int lane = threadIdx.x & 63;
    if (lane == 0) { sv[wid] = v; sc[wid] = c; }
    __syncthreads();
    if (threadIdx.x == 0) {
        float tv = sv[0] + sv[1] + sv[2] + sv[3];
        int   tc = sc[0] + sc[1] + sc[2] + sc[3];
        atomicAdd(ws_sum, (double)tv);
        atomicAdd(ws_cnt, (unsigned long long)tc);
    }
}

__global__ void rsl_final(const double* __restrict__ ws_sum,
                          const unsigned long long* __restrict__ ws_cnt,
                          float* __restrict__ out)
{
    if (blockIdx.x == 0 && threadIdx.x == 0) {
        double c = (double)ws_cnt[0];
        out[0] = (float)(ws_sum[0] / (c > 0.0 ? c : 1.0));
    }
}

extern "C" void kernel_launch(void* const* d_in, const int* in_sizes, int n_in,
                              void* d_out, int out_size, void* d_ws, size_t ws_size,
                              hipStream_t stream)
{
    const float* pred = (const float*)d_in[0];   // (B, D, H, W) fp32
    const float* cls  = (const float*)d_in[1];   // (150, 512) fp32 (pre-normalized)
    const int*   idx  = (const int*)d_in[2];     // (B, 1, H, W) int32
    const int*   lut  = (const int*)d_in[3];     // (512,) int32

    float* out = (float*)d_out;
    double* wsd = (double*)d_ws;
    unsigned long long* wsc = (unsigned long long*)((char*)d_ws + 8);

    // zero accumulators every launch (harness does not re-poison between replays)
    hipMemsetAsync(d_ws, 0, 16, stream);

    const int total = B_DIM * HW_DIM;            // 262144 pixels
    rsl_main<<<total / 256, 256, 0, stream>>>(pred, cls, idx, lut, wsd, wsc);
    rsl_final<<<1, 64, 0, stream>>>(wsd, wsc, out);
}

// Round 2
// 167.567 us; speedup vs baseline: 21.3146x; 21.3146x over previous
//
#include <hip/hip_runtime.h>
#include <hip/hip_bf16.h>

// RelativeSemanticLoss via bf16 MFMA GEMM + fused softmax-NLL epilogue.
// sim = pred(M=262144,K=512) x cls^T(K=512,N=150), nll = lse(sim/T) - sim[label]/T
// Wave = 32 pixels x 160 classes (2 mt x 10 nt of 16x16x32 MFMA tiles).

#define NUM_CLS 150
#define NT_TILES 10      // 160 padded classes
#define D_DIM   512
#define HW_DIM  65536
#define IGNORE_L 255

typedef __attribute__((ext_vector_type(8))) short bf16x8;
typedef __attribute__((ext_vector_type(4))) float f32x4;
typedef __attribute__((ext_vector_type(4))) unsigned int u32x4;

static __device__ __forceinline__ short f2bf(float f) {
    __hip_bfloat16 h = __float2bfloat16(f);   // RNE
    return __builtin_bit_cast(short, h);
}

// Pack cls (150x512 fp32) -> bf16 fragments in lane-linear order:
// packed[(s*10+nt)*512 + l*8 + j] (ushort units) = bf16(cls[nt*16+(l&15)][s*32+(l>>4)*8+j])
__global__ void rsl_pack_cls(const float* __restrict__ cls,
                             unsigned short* __restrict__ packed)
{
    int t = blockIdx.x * 256 + threadIdx.x;      // 0 .. 16*10*64-1
    if (t >= 16 * NT_TILES * 64) return;
    int s  = t / (NT_TILES * 64);
    int r  = t - s * (NT_TILES * 64);
    int nt = r >> 6;
    int l  = r & 63;
    int c  = nt * 16 + (l & 15);
    int k  = s * 32 + (l >> 4) * 8;
    unsigned short v[8];
#pragma unroll
    for (int j = 0; j < 8; ++j)
        v[j] = (c < NUM_CLS) ? (unsigned short)f2bf(cls[c * D_DIM + k + j]) : (unsigned short)0;
    u32x4 w;
#pragma unroll
    for (int q = 0; q < 4; ++q)
        w[q] = (unsigned int)v[2 * q] | ((unsigned int)v[2 * q + 1] << 16);
    *(u32x4*)(packed + (size_t)(s * NT_TILES + nt) * 512 + (size_t)l * 8) = w;
}

__global__ __launch_bounds__(256, 2)
void rsl_mfma(const float* __restrict__ pred,
              const unsigned short* __restrict__ packed,
              const int*   __restrict__ idx,
              const int*   __restrict__ lut,
              double* __restrict__ ws_sum,
              unsigned long long* __restrict__ ws_cnt)
{
    const int lane = threadIdx.x & 63;
    const int wid  = threadIdx.x >> 6;
    const int row  = lane & 15;      // M-index within tile (input frag) / N-index (output)
    const int g    = lane >> 4;      // k-chunk group (input) / row-group (output)

    const int pixbase = blockIdx.x * 128 + wid * 32;   // global pixel id (never straddles b: 65536%128==0)
    const int b  = pixbase >> 16;
    const int p0 = pixbase & 0xFFFF;
    const float* pb = pred + (size_t)b * D_DIM * HW_DIM;

    f32x4 acc[2][NT_TILES] = {};

    for (int s = 0; s < 16; ++s) {
        // pixel (A/M) fragments: row = lane&15, k = s*32 + g*8 + j
        bf16x8 pf[2];
#pragma unroll
        for (int mt = 0; mt < 2; ++mt) {
            const float* src = pb + (size_t)(s * 32 + g * 8) * HW_DIM + (p0 + mt * 16 + row);
#pragma unroll
            for (int j = 0; j < 8; ++j)
                pf[mt][j] = f2bf(src[(size_t)j * HW_DIM]);
        }
        // cls (B/N) fragments: pre-packed lane-linear, fully coalesced 16B/lane
        const unsigned short* base = packed + (size_t)(s * NT_TILES) * 512 + (size_t)lane * 8;
        bf16x8 cf[NT_TILES];
#pragma unroll
        for (int nt = 0; nt < NT_TILES; ++nt)
            cf[nt] = *(const bf16x8*)(base + nt * 512);
#pragma unroll
        for (int mt = 0; mt < 2; ++mt)
#pragma unroll
            for (int nt = 0; nt < NT_TILES; ++nt)
                acc[mt][nt] = __builtin_amdgcn_mfma_f32_16x16x32_bf16(pf[mt], cf[nt], acc[mt][nt], 0, 0, 0);
    }

    // Epilogue. C/D: class = nt*16 + (lane&15), pixel = mt*16 + g*4 + j (m89 map).
    const float invT = 1.0f / 0.07f;
    float local_sum = 0.f;
    int   local_cnt = 0;
#pragma unroll
    for (int mt = 0; mt < 2; ++mt) {
#pragma unroll
        for (int j = 0; j < 4; ++j) {
            const int pixg = pixbase + mt * 16 + g * 4 + j;
            const int lab  = lut[idx[pixg]];
            const bool valid = (lab != IGNORE_L);

            float m = -1e30f;
#pragma unroll
            for (int nt = 0; nt < NT_TILES; ++nt) {
                int c = nt * 16 + row;
                float v = (c < NUM_CLS) ? acc[mt][nt][j] : -1e30f;
                m = fmaxf(m, v);
            }
#pragma unroll
            for (int o = 8; o >= 1; o >>= 1) m = fmaxf(m, __shfl_xor(m, o));

            float ssum = 0.f, slab = 0.f;
#pragma unroll
            for (int nt = 0; nt < NT_TILES; ++nt) {
                int c = nt * 16 + row;
                if (c < NUM_CLS) {
                    float v = acc[mt][nt][j];
                    ssum += __expf((v - m) * invT);
                    slab += (c == lab) ? v : 0.f;
                }
            }
#pragma unroll
            for (int o = 8; o >= 1; o >>= 1) {
                ssum += __shfl_xor(ssum, o);
                slab += __shfl_xor(slab, o);
            }
            if (row == 0 && valid) {
                local_sum += (m - slab) * invT + __logf(ssum);
                local_cnt += 1;
            }
        }
    }

    // wave(64) reduce
#pragma unroll
    for (int o = 32; o >= 1; o >>= 1) {
        local_sum += __shfl_down(local_sum, o);
        local_cnt += __shfl_down(local_cnt, o);
    }
    __shared__ float sv[4];
    __shared__ int   sc[4];
    if (lane == 0) { sv[wid] = local_sum; sc[wid] = local_cnt; }
    __syncthreads();
    if (threadIdx.x == 0) {
        float tv = sv[0] + sv[1] + sv[2] + sv[3];
        int   tc = sc[0] + sc[1] + sc[2] + sc[3];
        atomicAdd(ws_sum, (double)tv);
        atomicAdd(ws_cnt, (unsigned long long)tc);
    }
}

__global__ void rsl_final(const double* __restrict__ ws_sum,
                          const unsigned long long* __restrict__ ws_cnt,
                          float* __restrict__ out)
{
    if (threadIdx.x == 0) {
        double c = (double)ws_cnt[0];
        out[0] = (float)(ws_sum[0] / (c > 0.0 ? c : 1.0));
    }
}

extern "C" void kernel_launch(void* const* d_in, const int* in_sizes, int n_in,
                              void* d_out, int out_size, void* d_ws, size_t ws_size,
                              hipStream_t stream)
{
    const float* pred = (const float*)d_in[0];   // (4, 512, 256, 256) fp32
    const float* cls  = (const float*)d_in[1];   // (150, 512) fp32
    const int*   idx  = (const int*)d_in[2];     // (4, 1, 256, 256) int32
    const int*   lut  = (const int*)d_in[3];     // (512,) int32
    float* out = (float*)d_out;

    double* wsd = (double*)d_ws;
    unsigned long long* wsc = (unsigned long long*)((char*)d_ws + 8);
    unsigned short* packed = (unsigned short*)((char*)d_ws + 1024);  // 160 KB

    hipMemsetAsync(d_ws, 0, 16, stream);
    rsl_pack_cls<<<40, 256, 0, stream>>>(cls, packed);

    const int total = 4 * HW_DIM;                 // 262144 pixels
    rsl_mfma<<<total / 128, 256, 0, stream>>>(pred, packed, idx, lut, wsd, wsc);
    rsl_final<<<1, 64, 0, stream>>>(wsd, wsc, out);
}

// Round 3
// 162.596 us; speedup vs baseline: 21.9662x; 1.0306x over previous
//
#include <hip/hip_runtime.h>
#include <hip/hip_bf16.h>

// RelativeSemanticLoss via bf16 MFMA GEMM + fused softmax-NLL epilogue.
// sim = pred(M=262144,K=512) x cls^T(K=512,N=150), nll = lse(sim/T) - sim[label]/T
// Wave = 32 pixels x 160 classes (2 mt x 10 nt of 16x16x32 MFMA tiles).
// R3: software-prefetch pred loads across the MFMA phase; ws zeroed in pack kernel.

#define NUM_CLS 150
#define NT_TILES 10      // 160 padded classes
#define D_DIM   512
#define HW_DIM  65536
#define IGNORE_L 255

typedef __attribute__((ext_vector_type(8))) short bf16x8;
typedef __attribute__((ext_vector_type(4))) float f32x4;
typedef __attribute__((ext_vector_type(4))) unsigned int u32x4;

static __device__ __forceinline__ short f2bf(float f) {
    __hip_bfloat16 h = __float2bfloat16(f);   // RNE
    return __builtin_bit_cast(short, h);
}

// Pack cls (150x512 fp32) -> bf16 fragments in lane-linear order:
// packed[(s*10+nt)*512 + l*8 + j] (ushort units) = bf16(cls[nt*16+(l&15)][s*32+(l>>4)*8+j])
// Also zeroes the ws accumulators (replaces hipMemsetAsync).
__global__ void rsl_pack_cls(const float* __restrict__ cls,
                             unsigned short* __restrict__ packed,
                             double* __restrict__ ws_sum,
                             unsigned long long* __restrict__ ws_cnt)
{
    int t = blockIdx.x * 256 + threadIdx.x;      // 0 .. 16*10*64-1
    if (t == 0) { ws_sum[0] = 0.0; ws_cnt[0] = 0ull; }
    if (t >= 16 * NT_TILES * 64) return;
    int s  = t / (NT_TILES * 64);
    int r  = t - s * (NT_TILES * 64);
    int nt = r >> 6;
    int l  = r & 63;
    int c  = nt * 16 + (l & 15);
    int k  = s * 32 + (l >> 4) * 8;
    unsigned short v[8];
#pragma unroll
    for (int j = 0; j < 8; ++j)
        v[j] = (c < NUM_CLS) ? (unsigned short)f2bf(cls[c * D_DIM + k + j]) : (unsigned short)0;
    u32x4 w;
#pragma unroll
    for (int q = 0; q < 4; ++q)
        w[q] = (unsigned int)v[2 * q] | ((unsigned int)v[2 * q + 1] << 16);
    *(u32x4*)(packed + (size_t)(s * NT_TILES + nt) * 512 + (size_t)l * 8) = w;
}

__global__ __launch_bounds__(256, 2)
void rsl_mfma(const float* __restrict__ pred,
              const unsigned short* __restrict__ packed,
              const int*   __restrict__ idx,
              const int*   __restrict__ lut,
              double* __restrict__ ws_sum,
              unsigned long long* __restrict__ ws_cnt)
{
    const int lane = threadIdx.x & 63;
    const int wid  = threadIdx.x >> 6;
    const int row  = lane & 15;      // M-index within tile (input frag) / N-index (output)
    const int g    = lane >> 4;      // k-chunk group (input) / row-group (output)

    const int pixbase = blockIdx.x * 128 + wid * 32;   // never straddles b (65536%128==0)
    const int b  = pixbase >> 16;
    const int p0 = pixbase & 0xFFFF;
    const float* pb = pred + (size_t)b * D_DIM * HW_DIM
                    + (size_t)(g * 8) * HW_DIM + (p0 + row);   // lane-resolved base

    f32x4 acc[2][NT_TILES] = {};

    // prologue: load + convert s=0 pred fragments
    bf16x8 pf[2];
#pragma unroll
    for (int mt = 0; mt < 2; ++mt) {
        const float* src = pb + mt * 16;
#pragma unroll
        for (int j = 0; j < 8; ++j)
            pf[mt][j] = f2bf(src[(size_t)j * HW_DIM]);
    }

    for (int s = 0; s < 16; ++s) {
        // issue next-s pred loads (raw fp32) BEFORE the MFMA block.
        // tail (s=15) re-reads s=15's own data: L2-hit, keeps loop branch-free.
        const int sp = (s < 15) ? s + 1 : s;
        float praw[2][8];
#pragma unroll
        for (int mt = 0; mt < 2; ++mt) {
            const float* src = pb + (size_t)(sp * 32) * HW_DIM + mt * 16;
#pragma unroll
            for (int j = 0; j < 8; ++j)
                praw[mt][j] = src[(size_t)j * HW_DIM];
        }

        // cls (B/N) fragments: pre-packed lane-linear, coalesced 16B/lane (L2-resident)
        const unsigned short* base = packed + (size_t)(s * NT_TILES) * 512 + (size_t)lane * 8;
        bf16x8 cf[NT_TILES];
#pragma unroll
        for (int nt = 0; nt < NT_TILES; ++nt)
            cf[nt] = *(const bf16x8*)(base + nt * 512);

#pragma unroll
        for (int mt = 0; mt < 2; ++mt)
#pragma unroll
            for (int nt = 0; nt < NT_TILES; ++nt)
                acc[mt][nt] = __builtin_amdgcn_mfma_f32_16x16x32_bf16(pf[mt], cf[nt], acc[mt][nt], 0, 0, 0);

        // convert prefetched raws AFTER MFMAs: vmcnt wait lands here, hidden by MFMA phase
#pragma unroll
        for (int mt = 0; mt < 2; ++mt)
#pragma unroll
            for (int j = 0; j < 8; ++j)
                pf[mt][j] = f2bf(praw[mt][j]);
    }

    // Epilogue. C/D: class = nt*16 + (lane&15), pixel = mt*16 + g*4 + j (m89 map).
    const float invT = 1.0f / 0.07f;
    float local_sum = 0.f;
    int   local_cnt = 0;
#pragma unroll
    for (int mt = 0; mt < 2; ++mt) {
#pragma unroll
        for (int j = 0; j < 4; ++j) {
            const int pixg = pixbase + mt * 16 + g * 4 + j;
            const int lab  = lut[idx[pixg]];
            const bool valid = (lab != IGNORE_L);

            float m = -1e30f;
#pragma unroll
            for (int nt = 0; nt < NT_TILES; ++nt) {
                int c = nt * 16 + row;
                float v = (c < NUM_CLS) ? acc[mt][nt][j] : -1e30f;
                m = fmaxf(m, v);
            }
#pragma unroll
            for (int o = 8; o >= 1; o >>= 1) m = fmaxf(m, __shfl_xor(m, o));

            float ssum = 0.f, slab = 0.f;
#pragma unroll
            for (int nt = 0; nt < NT_TILES; ++nt) {
                int c = nt * 16 + row;
                if (c < NUM_CLS) {
                    float v = acc[mt][nt][j];
                    ssum += __expf((v - m) * invT);
                    slab += (c == lab) ? v : 0.f;
                }
            }
#pragma unroll
            for (int o = 8; o >= 1; o >>= 1) {
                ssum += __shfl_xor(ssum, o);
                slab += __shfl_xor(slab, o);
            }
            if (row == 0 && valid) {
                local_sum += (m - slab) * invT + __logf(ssum);
                local_cnt += 1;
            }
        }
    }

    // wave(64) reduce
#pragma unroll
    for (int o = 32; o >= 1; o >>= 1) {
        local_sum += __shfl_down(local_sum, o);
        local_cnt += __shfl_down(local_cnt, o);
    }
    __shared__ float sv[4];
    __shared__ int   sc[4];
    if (lane == 0) { sv[wid] = local_sum; sc[wid] = local_cnt; }
    __syncthreads();
    if (threadIdx.x == 0) {
        float tv = sv[0] + sv[1] + sv[2] + sv[3];
        int   tc = sc[0] + sc[1] + sc[2] + sc[3];
        atomicAdd(ws_sum, (double)tv);
        atomicAdd(ws_cnt, (unsigned long long)tc);
    }
}

__global__ void rsl_final(const double* __restrict__ ws_sum,
                          const unsigned long long* __restrict__ ws_cnt,
                          float* __restrict__ out)
{
    if (threadIdx.x == 0) {
        double c = (double)ws_cnt[0];
        out[0] = (float)(ws_sum[0] / (c > 0.0 ? c : 1.0));
    }
}

extern "C" void kernel_launch(void* const* d_in, const int* in_sizes, int n_in,
                              void* d_out, int out_size, void* d_ws, size_t ws_size,
                              hipStream_t stream)
{
    const float* pred = (const float*)d_in[0];   // (4, 512, 256, 256) fp32
    const float* cls  = (const float*)d_in[1];   // (150, 512) fp32
    const int*   idx  = (const int*)d_in[2];     // (4, 1, 256, 256) int32
    const int*   lut  = (const int*)d_in[3];     // (512,) int32
    float* out = (float*)d_out;

    double* wsd = (double*)d_ws;
    unsigned long long* wsc = (unsigned long long*)((char*)d_ws + 8);
    unsigned short* packed = (unsigned short*)((char*)d_ws + 1024);  // 160 KB

    rsl_pack_cls<<<40, 256, 0, stream>>>(cls, packed, wsd, wsc);

    const int total = 4 * HW_DIM;                 // 262144 pixels
    rsl_mfma<<<total / 128, 256, 0, stream>>>(pred, packed, idx, lut, wsd, wsc);
    rsl_final<<<1, 64, 0, stream>>>(wsd, wsc, out);
}

// Round 4
// 131.596 us; speedup vs baseline: 27.1409x; 1.2356x over previous
//
#include <hip/hip_runtime.h>
#include <hip/hip_bf16.h>

// RelativeSemanticLoss via bf16 MFMA GEMM + fused softmax-NLL epilogue.
// R4: async global_load_lds double-buffered staging of pred (fp32) and cls
// fragments; 2-phase pipeline (stage s+1 || compute s, one barrier/iter).

#define NUM_CLS 150
#define NT_TILES 10      // 160 padded classes
#define D_DIM   512
#define HW_DIM  65536
#define IGNORE_L 255

typedef __attribute__((ext_vector_type(8))) short bf16x8;
typedef __attribute__((ext_vector_type(4))) float f32x4;
typedef __attribute__((ext_vector_type(4))) unsigned int u32x4;

// async 16B/lane global->LDS: lds dest is WAVE-UNIFORM base (+lane*16 in HW),
// global src is per-lane (m104/m108).
#define GLOAD16(gsrc, ldst) \
    __builtin_amdgcn_global_load_lds((const __attribute__((address_space(1))) void*)(gsrc), \
                                     (__attribute__((address_space(3))) void*)(ldst), 16, 0, 0)

static __device__ __forceinline__ short f2bf(float f) {
    __hip_bfloat16 h = __float2bfloat16(f);   // RNE
    return __builtin_bit_cast(short, h);
}

// Pack cls (150x512 fp32) -> bf16 fragments in lane-linear order:
// packed[(s*10+nt)*512 + l*8 + j] (ushort) = bf16(cls[nt*16+(l&15)][s*32+(l>>4)*8+j])
// Also zeroes the ws accumulators.
__global__ void rsl_pack_cls(const float* __restrict__ cls,
                             unsigned short* __restrict__ packed,
                             double* __restrict__ ws_sum,
                             unsigned long long* __restrict__ ws_cnt)
{
    int t = blockIdx.x * 256 + threadIdx.x;      // 0 .. 16*10*64-1
    if (t == 0) { ws_sum[0] = 0.0; ws_cnt[0] = 0ull; }
    if (t >= 16 * NT_TILES * 64) return;
    int s  = t / (NT_TILES * 64);
    int r  = t - s * (NT_TILES * 64);
    int nt = r >> 6;
    int l  = r & 63;
    int c  = nt * 16 + (l & 15);
    int k  = s * 32 + (l >> 4) * 8;
    unsigned short v[8];
#pragma unroll
    for (int j = 0; j < 8; ++j)
        v[j] = (c < NUM_CLS) ? (unsigned short)f2bf(cls[c * D_DIM + k + j]) : (unsigned short)0;
    u32x4 w;
#pragma unroll
    for (int q = 0; q < 4; ++q)
        w[q] = (unsigned int)v[2 * q] | ((unsigned int)v[2 * q + 1] << 16);
    *(u32x4*)(packed + (size_t)(s * NT_TILES + nt) * 512 + (size_t)l * 8) = w;
}

__global__ __launch_bounds__(256, 2)
void rsl_mfma(const float* __restrict__ pred,
              const unsigned short* __restrict__ packed,
              const int*   __restrict__ idx,
              const int*   __restrict__ lut,
              double* __restrict__ ws_sum,
              unsigned long long* __restrict__ ws_cnt)
{
    // LDS: pred tile [32 dims][128 pixels] fp32 (16KB) x2 + cls tile 10KB x2 = 52KB
    __shared__ float          sP[2][32][128];
    __shared__ unsigned short sC[2][NT_TILES][512];

    const int lane = threadIdx.x & 63;
    const int wid  = threadIdx.x >> 6;
    const int row  = lane & 15;      // M-idx in tile (A frag) / N-idx (C/D)
    const int g    = lane >> 4;      // k-group (A frag) / row-group (C/D)

    const int pixbase = blockIdx.x * 128;            // block pixel base (never straddles b)
    const int b  = pixbase >> 16;
    const int p0 = pixbase & 0xFFFF;
    // staging: lane covers dim-offset (lane>>5), pixels (lane&31)*4 .. +3 (16B)
    const float* pstage = pred + (size_t)b * D_DIM * HW_DIM
                        + (size_t)(lane >> 5) * HW_DIM + (p0 + (lane & 31) * 4);

    f32x4 acc[2][NT_TILES] = {};

    // ---- prologue: stage s=0 ----
    {
#pragma unroll
        for (int tt = 0; tt < 4; ++tt) {
            const int t = wid * 4 + tt;              // dim pair index 0..15
            GLOAD16(pstage + (size_t)(2 * t) * HW_DIM, &sP[0][2 * t][0]);
        }
        for (int nt = wid; nt < NT_TILES; nt += 4)
            GLOAD16(packed + (size_t)nt * 512 + (size_t)lane * 8, &sC[0][nt][0]);
    }
    __syncthreads();

    for (int s = 0; s < 16; ++s) {
        const int cur = s & 1;
        // ---- stage s+1 into the other buffer (async) ----
        if (s < 15) {
            const float* srcb = pstage + (size_t)((s + 1) * 32) * HW_DIM;
#pragma unroll
            for (int tt = 0; tt < 4; ++tt) {
                const int t = wid * 4 + tt;
                GLOAD16(srcb + (size_t)(2 * t) * HW_DIM, &sP[cur ^ 1][2 * t][0]);
            }
            const unsigned short* csrc = packed + (size_t)((s + 1) * NT_TILES) * 512 + (size_t)lane * 8;
            for (int nt = wid; nt < NT_TILES; nt += 4)
                GLOAD16(csrc + (size_t)nt * 512, &sC[cur ^ 1][nt][0]);
        }

        // ---- compute on current buffer ----
        bf16x8 pf[2];
#pragma unroll
        for (int mt = 0; mt < 2; ++mt)
#pragma unroll
            for (int j = 0; j < 8; ++j)
                pf[mt][j] = f2bf(sP[cur][g * 8 + j][wid * 32 + mt * 16 + row]);

#pragma unroll
        for (int nt = 0; nt < NT_TILES; ++nt) {
            bf16x8 cf = *(const bf16x8*)&sC[cur][nt][lane * 8];
#pragma unroll
            for (int mt = 0; mt < 2; ++mt)
                acc[mt][nt] = __builtin_amdgcn_mfma_f32_16x16x32_bf16(pf[mt], cf, acc[mt][nt], 0, 0, 0);
        }
        __syncthreads();   // drain (vmcnt0+lgkm0) + barrier: next tile ready, buffers safe
    }

    // ---- epilogue. C/D: class = nt*16 + row, pixel = wid*32 + mt*16 + g*4 + j ----
    const float invT = 1.0f / 0.07f;
    float local_sum = 0.f;
    int   local_cnt = 0;
#pragma unroll
    for (int mt = 0; mt < 2; ++mt) {
#pragma unroll
        for (int j = 0; j < 4; ++j) {
            const int pixg = pixbase + wid * 32 + mt * 16 + g * 4 + j;
            const int lab  = lut[idx[pixg]];
            const bool valid = (lab != IGNORE_L);

            float m = -1e30f;
#pragma unroll
            for (int nt = 0; nt < NT_TILES; ++nt) {
                int c = nt * 16 + row;
                float v = (c < NUM_CLS) ? acc[mt][nt][j] : -1e30f;
                m = fmaxf(m, v);
            }
#pragma unroll
            for (int o = 8; o >= 1; o >>= 1) m = fmaxf(m, __shfl_xor(m, o));

            float ssum = 0.f, slab = 0.f;
#pragma unroll
            for (int nt = 0; nt < NT_TILES; ++nt) {
                int c = nt * 16 + row;
                if (c < NUM_CLS) {
                    float v = acc[mt][nt][j];
                    ssum += __expf((v - m) * invT);
                    slab += (c == lab) ? v : 0.f;
                }
            }
#pragma unroll
            for (int o = 8; o >= 1; o >>= 1) {
                ssum += __shfl_xor(ssum, o);
                slab += __shfl_xor(slab, o);
            }
            if (row == 0 && valid) {
                local_sum += (m - slab) * invT + __logf(ssum);
                local_cnt += 1;
            }
        }
    }

    // wave(64) reduce -> block -> global atomics
#pragma unroll
    for (int o = 32; o >= 1; o >>= 1) {
        local_sum += __shfl_down(local_sum, o);
        local_cnt += __shfl_down(local_cnt, o);
    }
    __shared__ float sv[4];
    __shared__ int   sc[4];
    if (lane == 0) { sv[wid] = local_sum; sc[wid] = local_cnt; }
    __syncthreads();
    if (threadIdx.x == 0) {
        float tv = sv[0] + sv[1] + sv[2] + sv[3];
        int   tc = sc[0] + sc[1] + sc[2] + sc[3];
        atomicAdd(ws_sum, (double)tv);
        atomicAdd(ws_cnt, (unsigned long long)tc);
    }
}

__global__ void rsl_final(const double* __restrict__ ws_sum,
                          const unsigned long long* __restrict__ ws_cnt,
                          float* __restrict__ out)
{
    if (threadIdx.x == 0) {
        double c = (double)ws_cnt[0];
        out[0] = (float)(ws_sum[0] / (c > 0.0 ? c : 1.0));
    }
}

extern "C" void kernel_launch(void* const* d_in, const int* in_sizes, int n_in,
                              void* d_out, int out_size, void* d_ws, size_t ws_size,
                              hipStream_t stream)
{
    const float* pred = (const float*)d_in[0];   // (4, 512, 256, 256) fp32
    const float* cls  = (const float*)d_in[1];   // (150, 512) fp32
    const int*   idx  = (const int*)d_in[2];     // (4, 1, 256, 256) int32
    const int*   lut  = (const int*)d_in[3];     // (512,) int32
    float* out = (float*)d_out;

    double* wsd = (double*)d_ws;
    unsigned long long* wsc = (unsigned long long*)((char*)d_ws + 8);
    unsigned short* packed = (unsigned short*)((char*)d_ws + 1024);  // 160 KB

    rsl_pack_cls<<<40, 256, 0, stream>>>(cls, packed, wsd, wsc);

    const int total = 4 * HW_DIM;                 // 262144 pixels
    rsl_mfma<<<total / 128, 256, 0, stream>>>(pred, packed, idx, lut, wsd, wsc);
    rsl_final<<<1, 64, 0, stream>>>(wsd, wsc, out);
}